// Round 1
// baseline (1486.678 us; speedup 1.0000x reference)
//
#include <hip/hip_runtime.h>
#include <math.h>

#define N_NODES 100000
#define N_EDGES 1600000
#define E_TOT   (N_EDGES + N_NODES)

// ---------------------------------------------------------------------------
// GEMM1: h1[N,128] = x[N,128] @ W1[128,128]; fused alpha_src/alpha_dst
// (per-head dot with att vectors). W1 staged in LDS (64KB exactly).
// Block 256 = 8 teams of 32 lanes; team handles 4 nodes (micro-tile),
// thread handles 4 consecutive columns via float4.
// ---------------------------------------------------------------------------
__global__ __launch_bounds__(256) void gemm1_k(
    const float* __restrict__ x, const float* __restrict__ W1,
    const float* __restrict__ as1, const float* __restrict__ ad1,
    float* __restrict__ h1, float* __restrict__ asrc, float* __restrict__ adst)
{
    __shared__ float4 Ws[128 * 32];   // W1[k][c4] as float4 over columns, 64KB
    const int t = threadIdx.x;
    const float4* W4 = (const float4*)W1;
#pragma unroll
    for (int i = 0; i < 16; ++i) Ws[t + i * 256] = W4[t + i * 256];
    __syncthreads();

    const int team = t >> 5;          // 0..7
    const int L    = t & 31;          // lane in team; cols L*4 .. L*4+3
    const int node0 = blockIdx.x * 32 + team * 4;

    const float* xr0 = x + (size_t)(node0 + 0) * 128;
    const float* xr1 = x + (size_t)(node0 + 1) * 128;
    const float* xr2 = x + (size_t)(node0 + 2) * 128;
    const float* xr3 = x + (size_t)(node0 + 3) * 128;

    float4 accs[4];
#pragma unroll
    for (int i = 0; i < 4; ++i) accs[i] = make_float4(0.f, 0.f, 0.f, 0.f);

    for (int k = 0; k < 128; ++k) {
        float4 w = Ws[k * 32 + L];
        float a = xr0[k], b = xr1[k], c = xr2[k], d = xr3[k];
        accs[0].x += w.x * a; accs[0].y += w.y * a; accs[0].z += w.z * a; accs[0].w += w.w * a;
        accs[1].x += w.x * b; accs[1].y += w.y * b; accs[1].z += w.z * b; accs[1].w += w.w * b;
        accs[2].x += w.x * c; accs[2].y += w.y * c; accs[2].z += w.z * c; accs[2].w += w.w * c;
        accs[3].x += w.x * d; accs[3].y += w.y * d; accs[3].z += w.z * d; accs[3].w += w.w * d;
    }

    float4 as4 = ((const float4*)as1)[L];   // att vectors flattened [128]
    float4 ad4 = ((const float4*)ad1)[L];
#pragma unroll
    for (int nt = 0; nt < 4; ++nt) {
        int node = node0 + nt;
        ((float4*)(h1 + (size_t)node * 128))[L] = accs[nt];
        float ps = accs[nt].x * as4.x + accs[nt].y * as4.y + accs[nt].z * as4.z + accs[nt].w * as4.w;
        float pd = accs[nt].x * ad4.x + accs[nt].y * ad4.y + accs[nt].z * ad4.z + accs[nt].w * ad4.w;
#pragma unroll
        for (int off = 1; off < 16; off <<= 1) {
            ps += __shfl_xor(ps, off);
            pd += __shfl_xor(pd, off);
        }
        if ((L & 15) == 0) {                 // lanes 0,16 of team -> heads 0,1
            int h = L >> 4;
            asrc[node * 2 + h] = ps;
            adst[node * 2 + h] = pd;
        }
    }
}

// ---------------------------------------------------------------------------
// Edge pass: w[e,h] = exp(leaky_relu(asrc[s,h] + adst[d,h])); atomic sum per dst.
// Max-subtraction skipped (e bounded; analytically identical softmax).
// ---------------------------------------------------------------------------
template<int H>
__global__ __launch_bounds__(256) void edge_w_k(
    const int* __restrict__ ei, const float* __restrict__ asrc,
    const float* __restrict__ adst, float* __restrict__ w, float* __restrict__ ssum)
{
    int e = blockIdx.x * 256 + threadIdx.x;
    if (e >= E_TOT) return;
    int s, d;
    if (e < N_EDGES) { s = ei[e]; d = ei[N_EDGES + e]; }
    else             { s = d = e - N_EDGES; }
#pragma unroll
    for (int h = 0; h < H; ++h) {
        float v = asrc[s * H + h] + adst[d * H + h];
        v = v > 0.f ? v : 0.2f * v;
        float ex = __expf(v);
        w[e * H + h] = ex;
        atomicAdd(&ssum[d * H + h], ex);
    }
}

// ---------------------------------------------------------------------------
// Aggregation: acc[d, c] += w[e, h(c)] * hsrc[s, c]   (atomic scatter)
// ---------------------------------------------------------------------------
template<int C, int H>
__global__ __launch_bounds__(256) void agg_k(
    const int* __restrict__ ei, const float* __restrict__ w,
    const float* __restrict__ hsrc, float* __restrict__ acc)
{
    int gid = blockIdx.x * 256 + threadIdx.x;
    if (gid >= E_TOT * C) return;
    int e = gid / C;
    int c = gid - e * C;
    int s, d;
    if (e < N_EDGES) { s = ei[e]; d = ei[N_EDGES + e]; }
    else             { s = d = e - N_EDGES; }
    int h = (H == 1) ? 0 : (c / (C / H));
    atomicAdd(&acc[(size_t)d * C + c], w[e * H + h] * hsrc[(size_t)s * C + c]);
}

// ---------------------------------------------------------------------------
// Layer-1 epilogue: normalize by softmax denom, + bias, ELU. In place.
// ---------------------------------------------------------------------------
__global__ __launch_bounds__(256) void norm_elu_k(
    float* __restrict__ acc, const float* __restrict__ ssum, const float* __restrict__ b1)
{
    int gid = blockIdx.x * 256 + threadIdx.x;     // grid covers N*128 exactly
    int n = gid >> 7, c = gid & 127, h = c >> 6;
    float v = acc[gid] / (ssum[n * 2 + h] + 1e-16f) + b1[c];
    acc[gid] = v > 0.f ? v : expm1f(v);
}

// ---------------------------------------------------------------------------
// GEMM2: h2[N,40] = in[N,128] @ W2[128,40]; fused alpha2 reductions.
// W2 staged transposed+padded (stride 132 -> b128 reads at the 5-cyc floor).
// Block 256 = 4 waves; wave owns 8 nodes; lanes 0..39 = output columns.
// ---------------------------------------------------------------------------
__global__ __launch_bounds__(256) void gemm2_k(
    const float* __restrict__ in, const float* __restrict__ W2,
    const float* __restrict__ as2, const float* __restrict__ ad2,
    float* __restrict__ h2, float* __restrict__ asrc, float* __restrict__ adst)
{
    __shared__ float WsT[40 * 132];
    __shared__ float as_s[40], ad_s[40];
    const int t = threadIdx.x;
    for (int i = t; i < 5120; i += 256) {
        int k = i / 40, c = i - k * 40;
        WsT[c * 132 + k] = W2[i];
    }
    if (t < 40) { as_s[t] = as2[t]; ad_s[t] = ad2[t]; }
    __syncthreads();

    const int wv = t >> 6, L = t & 63;
    const int base = blockIdx.x * 32 + wv * 8;
    for (int ni = 0; ni < 8; ++ni) {
        int n = base + ni;
        const float4* row4 = (const float4*)(in + (size_t)n * 128);
        float a = 0.f;
        if (L < 40) {
            const float4* wrow = (const float4*)&WsT[L * 132];
            float4 a4 = make_float4(0.f, 0.f, 0.f, 0.f);
            for (int k4 = 0; k4 < 32; ++k4) {
                float4 xv = row4[k4];
                float4 wvv = wrow[k4];
                a4.x += xv.x * wvv.x; a4.y += xv.y * wvv.y;
                a4.z += xv.z * wvv.z; a4.w += xv.w * wvv.w;
            }
            a = (a4.x + a4.y) + (a4.z + a4.w);
            h2[(size_t)n * 40 + L] = a;
        }
        float ps = (L < 40) ? a * as_s[L] : 0.f;
        float pd = (L < 40) ? a * ad_s[L] : 0.f;
#pragma unroll
        for (int off = 32; off; off >>= 1) {
            ps += __shfl_xor(ps, off);
            pd += __shfl_xor(pd, off);
        }
        if (L == 0) { asrc[n] = ps; adst[n] = pd; }
    }
}

// ---------------------------------------------------------------------------
// Final: normalize layer-2 agg, + bias, log_softmax over 40 classes.
// Wave per node, lanes 0..39 active.
// ---------------------------------------------------------------------------
__global__ __launch_bounds__(256) void final_k(
    const float* __restrict__ acc2, const float* __restrict__ s2,
    const float* __restrict__ b2, float* __restrict__ out)
{
    int n = blockIdx.x * 4 + (threadIdx.x >> 6);
    int c = threadIdx.x & 63;
    bool act = c < 40;
    float inv = 1.f / (s2[n] + 1e-16f);
    float v = act ? acc2[(size_t)n * 40 + c] * inv + b2[c] : -1e30f;
    float mx = v;
#pragma unroll
    for (int off = 32; off; off >>= 1) mx = fmaxf(mx, __shfl_xor(mx, off));
    float ex = act ? __expf(v - mx) : 0.f;
#pragma unroll
    for (int off = 32; off; off >>= 1) ex += __shfl_xor(ex, off);
    if (act) out[(size_t)n * 40 + c] = v - mx - logf(ex);
}

// ---------------------------------------------------------------------------
extern "C" void kernel_launch(void* const* d_in, const int* in_sizes, int n_in,
                              void* d_out, int out_size, void* d_ws, size_t ws_size,
                              hipStream_t stream)
{
    const float* x   = (const float*)d_in[0];
    const int*   ei  = (const int*)d_in[1];
    const float* W1  = (const float*)d_in[2];
    const float* as1 = (const float*)d_in[3];
    const float* ad1 = (const float*)d_in[4];
    const float* b1  = (const float*)d_in[5];
    const float* W2  = (const float*)d_in[6];
    const float* as2 = (const float*)d_in[7];
    const float* ad2 = (const float*)d_in[8];
    const float* b2  = (const float*)d_in[9];
    float* out = (float*)d_out;

    float* ws = (float*)d_ws;
    // workspace layout (floats); total 33.9M floats = 135.6 MB
    float* h1    = ws;                 // N*128 = 12.8M ; later reused as h2pre
    float* acc1  = ws + 12800000;      // N*128 (zeroed; becomes out1 in place)
    float* acc2  = ws + 25600000;      // N*40  (zeroed)
    float* s1    = ws + 29600000;      // 2N    (zeroed)
    float* s2    = ws + 29800000;      // N     (zeroed)
    float* asrc1 = ws + 29900000;      // 2N
    float* adst1 = ws + 30100000;      // 2N
    float* asrc2 = ws + 30300000;      // N
    float* adst2 = ws + 30400000;      // N
    float* w1    = ws + 30500000;      // E_TOT*2 = 3.4M ; w2 reuses this region
    float* w2    = w1;

    // zero accumulators: acc1 + acc2 + s1 + s2 are contiguous
    hipMemsetAsync(acc1, 0, (size_t)(12800000 + 4000000 + 200000 + 100000) * sizeof(float), stream);

    // layer 1
    gemm1_k<<<3125, 256, 0, stream>>>(x, W1, as1, ad1, h1, asrc1, adst1);
    edge_w_k<2><<<(E_TOT + 255) / 256, 256, 0, stream>>>(ei, asrc1, adst1, w1, s1);
    agg_k<128, 2><<<850000, 256, 0, stream>>>(ei, w1, h1, acc1);
    norm_elu_k<<<50000, 256, 0, stream>>>(acc1, s1, b1);

    // layer 2 (h2pre reuses h1's region)
    float* h2 = h1;
    gemm2_k<<<3125, 256, 0, stream>>>(acc1, W2, as2, ad2, h2, asrc2, adst2);
    edge_w_k<1><<<(E_TOT + 255) / 256, 256, 0, stream>>>(ei, asrc2, adst2, w2, s2);
    agg_k<40, 1><<<265625, 256, 0, stream>>>(ei, w2, h2, acc2);

    // epilogue
    final_k<<<25000, 256, 0, stream>>>(acc2, s2, b2, out);
}

// Round 2
// 703.451 us; speedup vs baseline: 2.1134x; 2.1134x over previous
//
#include <hip/hip_runtime.h>
#include <math.h>

#define N_NODES 100000
#define N_EDGES 1600000
#define E_TOT   (N_EDGES + N_NODES)
#define NBLK_SCAN 391   // ceil(N_NODES/256)

// ---------------------------------------------------------------------------
// GEMM1: h1[N,128] = x[N,128] @ W1[128,128]; fused alpha_src/alpha_dst.
// W1 staged in LDS (64KB). 8 teams of 32 lanes; team = 4 nodes; lane = 4 cols.
// ---------------------------------------------------------------------------
__global__ __launch_bounds__(256) void gemm1_k(
    const float* __restrict__ x, const float* __restrict__ W1,
    const float* __restrict__ as1, const float* __restrict__ ad1,
    float* __restrict__ h1, float* __restrict__ asrc, float* __restrict__ adst)
{
    __shared__ float4 Ws[128 * 32];
    const int t = threadIdx.x;
    const float4* W4 = (const float4*)W1;
#pragma unroll
    for (int i = 0; i < 16; ++i) Ws[t + i * 256] = W4[t + i * 256];
    __syncthreads();

    const int team = t >> 5;
    const int L    = t & 31;
    const int node0 = blockIdx.x * 32 + team * 4;

    const float* xr0 = x + (size_t)(node0 + 0) * 128;
    const float* xr1 = x + (size_t)(node0 + 1) * 128;
    const float* xr2 = x + (size_t)(node0 + 2) * 128;
    const float* xr3 = x + (size_t)(node0 + 3) * 128;

    float4 accs[4];
#pragma unroll
    for (int i = 0; i < 4; ++i) accs[i] = make_float4(0.f, 0.f, 0.f, 0.f);

    for (int k = 0; k < 128; ++k) {
        float4 w = Ws[k * 32 + L];
        float a = xr0[k], b = xr1[k], c = xr2[k], d = xr3[k];
        accs[0].x += w.x * a; accs[0].y += w.y * a; accs[0].z += w.z * a; accs[0].w += w.w * a;
        accs[1].x += w.x * b; accs[1].y += w.y * b; accs[1].z += w.z * b; accs[1].w += w.w * b;
        accs[2].x += w.x * c; accs[2].y += w.y * c; accs[2].z += w.z * c; accs[2].w += w.w * c;
        accs[3].x += w.x * d; accs[3].y += w.y * d; accs[3].z += w.z * d; accs[3].w += w.w * d;
    }

    float4 as4 = ((const float4*)as1)[L];
    float4 ad4 = ((const float4*)ad1)[L];
#pragma unroll
    for (int nt = 0; nt < 4; ++nt) {
        int node = node0 + nt;
        ((float4*)(h1 + (size_t)node * 128))[L] = accs[nt];
        float ps = accs[nt].x * as4.x + accs[nt].y * as4.y + accs[nt].z * as4.z + accs[nt].w * as4.w;
        float pd = accs[nt].x * ad4.x + accs[nt].y * ad4.y + accs[nt].z * ad4.z + accs[nt].w * ad4.w;
#pragma unroll
        for (int off = 1; off < 16; off <<= 1) {
            ps += __shfl_xor(ps, off);
            pd += __shfl_xor(pd, off);
        }
        if ((L & 15) == 0) {
            int h = L >> 4;
            asrc[node * 2 + h] = ps;
            adst[node * 2 + h] = pd;
        }
    }
}

// ---------------------------------------------------------------------------
// CSR build: count -> scan (3 kernels, deterministic) -> fill
// ---------------------------------------------------------------------------
__global__ __launch_bounds__(256) void count_k(const int* __restrict__ ei, int* __restrict__ deg)
{
    int e = blockIdx.x * 256 + threadIdx.x;
    if (e >= E_TOT) return;
    int d = (e < N_EDGES) ? ei[N_EDGES + e] : e - N_EDGES;
    atomicAdd(&deg[d], 1);
}

__global__ __launch_bounds__(256) void scan1_k(const int* __restrict__ deg, int* __restrict__ bsum)
{
    __shared__ int sm[256];
    int i = blockIdx.x * 256 + threadIdx.x;
    sm[threadIdx.x] = (i < N_NODES) ? deg[i] : 0;
    __syncthreads();
    for (int off = 128; off; off >>= 1) {
        if (threadIdx.x < off) sm[threadIdx.x] += sm[threadIdx.x + off];
        __syncthreads();
    }
    if (threadIdx.x == 0) bsum[blockIdx.x] = sm[0];
}

__global__ void scan2_k(int* __restrict__ bsum)   // 1 block x 64: exclusive scan in place
{
    int L = threadIdx.x;
    int carry = 0;
    for (int base = 0; base < NBLK_SCAN; base += 64) {
        int i = base + L;
        int v = (i < NBLK_SCAN) ? bsum[i] : 0;
        int x = v;
#pragma unroll
        for (int off = 1; off < 64; off <<= 1) {
            int y = __shfl_up(x, off);
            if (L >= off) x += y;
        }
        if (i < NBLK_SCAN) bsum[i] = x - v + carry;
        carry += __shfl(x, 63);
    }
}

__global__ __launch_bounds__(256) void scan3_k(
    const int* __restrict__ deg, const int* __restrict__ bpre, int* __restrict__ row_start)
{
    __shared__ int sm[256];
    int i = blockIdx.x * 256 + threadIdx.x;
    int v = (i < N_NODES) ? deg[i] : 0;
    sm[threadIdx.x] = v;
    __syncthreads();
    for (int off = 1; off < 256; off <<= 1) {
        int t = (threadIdx.x >= off) ? sm[threadIdx.x - off] : 0;
        __syncthreads();
        sm[threadIdx.x] += t;
        __syncthreads();
    }
    int excl = sm[threadIdx.x] - v + bpre[blockIdx.x];
    if (i <= N_NODES) row_start[i] = excl;
}

__global__ __launch_bounds__(256) void fill_k(
    const int* __restrict__ ei, const int* __restrict__ row_start,
    int* __restrict__ cursor, int* __restrict__ csr_src)
{
    int e = blockIdx.x * 256 + threadIdx.x;
    if (e >= E_TOT) return;
    int s, d;
    if (e < N_EDGES) { s = ei[e]; d = ei[N_EDGES + e]; }
    else             { s = d = e - N_EDGES; }
    int slot = row_start[d] + atomicAdd(&cursor[d], 1);
    csr_src[slot] = s;
}

// ---------------------------------------------------------------------------
// Edge softmax, CSR order, atomic-free. Wave (64 lanes) per dst node.
// Writes NORMALIZED coefficients.
// ---------------------------------------------------------------------------
__global__ __launch_bounds__(256) void edgew1_k(
    const int* __restrict__ csr_src, const int* __restrict__ row_start,
    const float2* __restrict__ asrc, const float2* __restrict__ adst,
    float2* __restrict__ wn)
{
    int node = blockIdx.x * 4 + (threadIdx.x >> 6);
    int L = threadIdx.x & 63;
    int b = row_start[node], e = row_start[node + 1];
    float2 ad = adst[node];
    float s0 = 0.f, s1 = 0.f;
    for (int j = b + L; j < e; j += 64) {
        float2 as = asrc[csr_src[j]];
        float v0 = as.x + ad.x; v0 = v0 > 0.f ? v0 : 0.2f * v0;
        float v1 = as.y + ad.y; v1 = v1 > 0.f ? v1 : 0.2f * v1;
        float e0 = __expf(v0), e1 = __expf(v1);
        wn[j] = make_float2(e0, e1);
        s0 += e0; s1 += e1;
    }
#pragma unroll
    for (int off = 32; off; off >>= 1) {
        s0 += __shfl_xor(s0, off);
        s1 += __shfl_xor(s1, off);
    }
    float i0 = 1.f / (s0 + 1e-16f), i1 = 1.f / (s1 + 1e-16f);
    for (int j = b + L; j < e; j += 64) {
        float2 w = wn[j];
        wn[j] = make_float2(w.x * i0, w.y * i1);
    }
}

__global__ __launch_bounds__(256) void edgew2_k(
    const int* __restrict__ csr_src, const int* __restrict__ row_start,
    const float* __restrict__ asrc, const float* __restrict__ adst,
    float* __restrict__ wn)
{
    int node = blockIdx.x * 4 + (threadIdx.x >> 6);
    int L = threadIdx.x & 63;
    int b = row_start[node], e = row_start[node + 1];
    float ad = adst[node];
    float s = 0.f;
    for (int j = b + L; j < e; j += 64) {
        float v = asrc[csr_src[j]] + ad;
        v = v > 0.f ? v : 0.2f * v;
        float ex = __expf(v);
        wn[j] = ex;
        s += ex;
    }
#pragma unroll
    for (int off = 32; off; off >>= 1) s += __shfl_xor(s, off);
    float inv = 1.f / (s + 1e-16f);
    for (int j = b + L; j < e; j += 64) wn[j] *= inv;
}

// ---------------------------------------------------------------------------
// Layer-1 aggregation: gather, no atomics. 32-lane team per node (lane = 4 cols).
// Fused bias + ELU epilogue.
// ---------------------------------------------------------------------------
__global__ __launch_bounds__(256) void agg1_k(
    const int* __restrict__ csr_src, const int* __restrict__ row_start,
    const float2* __restrict__ wn, const float* __restrict__ h1,
    const float* __restrict__ b1, float* __restrict__ out1)
{
    int team = threadIdx.x >> 5, L = threadIdx.x & 31;
    int node = blockIdx.x * 8 + team;
    int b = row_start[node], e = row_start[node + 1];
    int h = L >> 4;
    float4 acc = make_float4(0.f, 0.f, 0.f, 0.f);
    for (int j = b; j < e; ++j) {
        int s = csr_src[j];
        float2 wv = wn[j];
        float w = h ? wv.y : wv.x;
        float4 xv = ((const float4*)(h1 + (size_t)s * 128))[L];
        acc.x += w * xv.x; acc.y += w * xv.y; acc.z += w * xv.z; acc.w += w * xv.w;
    }
    float4 bb = ((const float4*)b1)[L];
    acc.x += bb.x; acc.y += bb.y; acc.z += bb.z; acc.w += bb.w;
    acc.x = acc.x > 0.f ? acc.x : expm1f(acc.x);
    acc.y = acc.y > 0.f ? acc.y : expm1f(acc.y);
    acc.z = acc.z > 0.f ? acc.z : expm1f(acc.z);
    acc.w = acc.w > 0.f ? acc.w : expm1f(acc.w);
    ((float4*)(out1 + (size_t)node * 128))[L] = acc;
}

// ---------------------------------------------------------------------------
// GEMM2: h2[N,40] = in[N,128] @ W2[128,40]; fused alpha2 reductions.
// ---------------------------------------------------------------------------
__global__ __launch_bounds__(256) void gemm2_k(
    const float* __restrict__ in, const float* __restrict__ W2,
    const float* __restrict__ as2, const float* __restrict__ ad2,
    float* __restrict__ h2, float* __restrict__ asrc, float* __restrict__ adst)
{
    __shared__ float WsT[40 * 132];
    __shared__ float as_s[40], ad_s[40];
    const int t = threadIdx.x;
    for (int i = t; i < 5120; i += 256) {
        int k = i / 40, c = i - k * 40;
        WsT[c * 132 + k] = W2[i];
    }
    if (t < 40) { as_s[t] = as2[t]; ad_s[t] = ad2[t]; }
    __syncthreads();

    const int wv = t >> 6, L = t & 63;
    const int base = blockIdx.x * 32 + wv * 8;
    for (int ni = 0; ni < 8; ++ni) {
        int n = base + ni;
        const float4* row4 = (const float4*)(in + (size_t)n * 128);
        float a = 0.f;
        if (L < 40) {
            const float4* wrow = (const float4*)&WsT[L * 132];
            float4 a4 = make_float4(0.f, 0.f, 0.f, 0.f);
            for (int k4 = 0; k4 < 32; ++k4) {
                float4 xv = row4[k4];
                float4 wvv = wrow[k4];
                a4.x += xv.x * wvv.x; a4.y += xv.y * wvv.y;
                a4.z += xv.z * wvv.z; a4.w += xv.w * wvv.w;
            }
            a = (a4.x + a4.y) + (a4.z + a4.w);
            h2[(size_t)n * 40 + L] = a;
        }
        float ps = (L < 40) ? a * as_s[L] : 0.f;
        float pd = (L < 40) ? a * ad_s[L] : 0.f;
#pragma unroll
        for (int off = 32; off; off >>= 1) {
            ps += __shfl_xor(ps, off);
            pd += __shfl_xor(pd, off);
        }
        if (L == 0) { asrc[n] = ps; adst[n] = pd; }
    }
}

// ---------------------------------------------------------------------------
// Layer-2 aggregation + bias + log_softmax fused. Wave per node, lanes 0..39.
// ---------------------------------------------------------------------------
__global__ __launch_bounds__(256) void agg2_k(
    const int* __restrict__ csr_src, const int* __restrict__ row_start,
    const float* __restrict__ wn, const float* __restrict__ h2,
    const float* __restrict__ b2, float* __restrict__ out)
{
    int node = blockIdx.x * 4 + (threadIdx.x >> 6);
    int L = threadIdx.x & 63;
    int b = row_start[node], e = row_start[node + 1];
    bool act = L < 40;
    float acc = 0.f;
    for (int j = b; j < e; ++j) {
        int s = csr_src[j];
        float w = wn[j];
        if (act) acc += w * h2[(size_t)s * 40 + L];
    }
    float v = act ? acc + b2[L] : -1e30f;
    float mx = v;
#pragma unroll
    for (int off = 32; off; off >>= 1) mx = fmaxf(mx, __shfl_xor(mx, off));
    float ex = act ? __expf(v - mx) : 0.f;
#pragma unroll
    for (int off = 32; off; off >>= 1) ex += __shfl_xor(ex, off);
    if (act) out[(size_t)node * 40 + L] = v - mx - logf(ex);
}

// ---------------------------------------------------------------------------
extern "C" void kernel_launch(void* const* d_in, const int* in_sizes, int n_in,
                              void* d_out, int out_size, void* d_ws, size_t ws_size,
                              hipStream_t stream)
{
    const float* x   = (const float*)d_in[0];
    const int*   ei  = (const int*)d_in[1];
    const float* W1  = (const float*)d_in[2];
    const float* as1 = (const float*)d_in[3];
    const float* ad1 = (const float*)d_in[4];
    const float* b1  = (const float*)d_in[5];
    const float* W2  = (const float*)d_in[6];
    const float* as2 = (const float*)d_in[7];
    const float* ad2 = (const float*)d_in[8];
    const float* b2  = (const float*)d_in[9];
    float* out = (float*)d_out;

    float* ws = (float*)d_ws;
    // workspace layout (float/int units of 4B); total ~31.7M = 126.8 MB
    float* h1    = ws;                   // N*128 ; reused as h2 (N*40) in layer 2
    float* out1  = ws + 12800000;        // N*128
    float* wn1   = ws + 25600000;        // E_TOT*2 ; reused as wn2 (E_TOT)
    float* asrc1 = ws + 29000000;        // 2N
    float* adst1 = ws + 29200000;        // 2N
    float* asrc2 = ws + 29400000;        // N
    float* adst2 = ws + 29500000;        // N
    int* deg       = (int*)(ws + 29600000);  // N
    int* cursor    = (int*)(ws + 29700000);  // N
    int* row_start = (int*)(ws + 29800000);  // N+1
    int* bsum      = (int*)(ws + 29950000);  // NBLK_SCAN
    int* csr_src   = (int*)(ws + 30000000);  // E_TOT

    // zero deg + cursor (contiguous, 200k ints = 800 KB)
    hipMemsetAsync(deg, 0, (size_t)200000 * sizeof(int), stream);

    // CSR build (shared by both layers)
    count_k<<<6641, 256, 0, stream>>>(ei, deg);
    scan1_k<<<NBLK_SCAN, 256, 0, stream>>>(deg, bsum);
    scan2_k<<<1, 64, 0, stream>>>(bsum);
    scan3_k<<<NBLK_SCAN, 256, 0, stream>>>(deg, bsum, row_start);
    fill_k<<<6641, 256, 0, stream>>>(ei, row_start, cursor, csr_src);

    // layer 1
    gemm1_k<<<3125, 256, 0, stream>>>(x, W1, as1, ad1, h1, asrc1, adst1);
    edgew1_k<<<25000, 256, 0, stream>>>(csr_src, row_start,
                                        (const float2*)asrc1, (const float2*)adst1,
                                        (float2*)wn1);
    agg1_k<<<12500, 256, 0, stream>>>(csr_src, row_start, (const float2*)wn1, h1, b1, out1);

    // layer 2 (h2 reuses h1 region; wn2 reuses wn1 region)
    float* h2 = h1;
    float* wn2 = wn1;
    gemm2_k<<<3125, 256, 0, stream>>>(out1, W2, as2, ad2, h2, asrc2, adst2);
    edgew2_k<<<25000, 256, 0, stream>>>(csr_src, row_start, asrc2, adst2, wn2);
    agg2_k<<<25000, 256, 0, stream>>>(csr_src, row_start, wn2, h2, b2, out);
}

// Round 3
// 636.139 us; speedup vs baseline: 2.3370x; 1.1058x over previous
//
#include <hip/hip_runtime.h>
#include <math.h>

#define N_NODES 100000
#define N_EDGES 1600000
#define E_TOT   (N_EDGES + N_NODES)
#define NBLK_SCAN 391   // ceil(N_NODES/256)

__device__ __forceinline__ float wexp(float v) {
    v = v > 0.f ? v : 0.2f * v;
    return __expf(v);
}

// ---------------------------------------------------------------------------
// GEMM1: h1[N,128] = x[N,128] @ W1[128,128]; fused alpha_src/alpha_dst.
// W1 staged in LDS (64KB). 8 teams of 32 lanes; team = 4 nodes; lane = 4 cols.
// ---------------------------------------------------------------------------
__global__ __launch_bounds__(256) void gemm1_k(
    const float* __restrict__ x, const float* __restrict__ W1,
    const float* __restrict__ as1, const float* __restrict__ ad1,
    float* __restrict__ h1, float* __restrict__ asrc, float* __restrict__ adst)
{
    __shared__ float4 Ws[128 * 32];
    const int t = threadIdx.x;
    const float4* W4 = (const float4*)W1;
#pragma unroll
    for (int i = 0; i < 16; ++i) Ws[t + i * 256] = W4[t + i * 256];
    __syncthreads();

    const int team = t >> 5;
    const int L    = t & 31;
    const int node0 = blockIdx.x * 32 + team * 4;

    const float* xr0 = x + (size_t)(node0 + 0) * 128;
    const float* xr1 = x + (size_t)(node0 + 1) * 128;
    const float* xr2 = x + (size_t)(node0 + 2) * 128;
    const float* xr3 = x + (size_t)(node0 + 3) * 128;

    float4 accs[4];
#pragma unroll
    for (int i = 0; i < 4; ++i) accs[i] = make_float4(0.f, 0.f, 0.f, 0.f);

    for (int k = 0; k < 128; ++k) {
        float4 w = Ws[k * 32 + L];
        float a = xr0[k], b = xr1[k], c = xr2[k], d = xr3[k];
        accs[0].x += w.x * a; accs[0].y += w.y * a; accs[0].z += w.z * a; accs[0].w += w.w * a;
        accs[1].x += w.x * b; accs[1].y += w.y * b; accs[1].z += w.z * b; accs[1].w += w.w * b;
        accs[2].x += w.x * c; accs[2].y += w.y * c; accs[2].z += w.z * c; accs[2].w += w.w * c;
        accs[3].x += w.x * d; accs[3].y += w.y * d; accs[3].z += w.z * d; accs[3].w += w.w * d;
    }

    float4 as4 = ((const float4*)as1)[L];
    float4 ad4 = ((const float4*)ad1)[L];
#pragma unroll
    for (int nt = 0; nt < 4; ++nt) {
        int node = node0 + nt;
        ((float4*)(h1 + (size_t)node * 128))[L] = accs[nt];
        float ps = accs[nt].x * as4.x + accs[nt].y * as4.y + accs[nt].z * as4.z + accs[nt].w * as4.w;
        float pd = accs[nt].x * ad4.x + accs[nt].y * ad4.y + accs[nt].z * ad4.z + accs[nt].w * ad4.w;
#pragma unroll
        for (int off = 1; off < 16; off <<= 1) {
            ps += __shfl_xor(ps, off);
            pd += __shfl_xor(pd, off);
        }
        if ((L & 15) == 0) {
            int h = L >> 4;
            asrc[node * 2 + h] = ps;
            adst[node * 2 + h] = pd;
        }
    }
}

// ---------------------------------------------------------------------------
// CSR build: count -> scan (3 kernels, deterministic) -> fill
// ---------------------------------------------------------------------------
__global__ __launch_bounds__(256) void count_k(const int* __restrict__ ei, int* __restrict__ deg)
{
    int e = blockIdx.x * 256 + threadIdx.x;
    if (e >= E_TOT) return;
    int d = (e < N_EDGES) ? ei[N_EDGES + e] : e - N_EDGES;
    atomicAdd(&deg[d], 1);
}

__global__ __launch_bounds__(256) void scan1_k(const int* __restrict__ deg, int* __restrict__ bsum)
{
    __shared__ int sm[256];
    int i = blockIdx.x * 256 + threadIdx.x;
    sm[threadIdx.x] = (i < N_NODES) ? deg[i] : 0;
    __syncthreads();
    for (int off = 128; off; off >>= 1) {
        if (threadIdx.x < off) sm[threadIdx.x] += sm[threadIdx.x + off];
        __syncthreads();
    }
    if (threadIdx.x == 0) bsum[blockIdx.x] = sm[0];
}

__global__ void scan2_k(int* __restrict__ bsum)   // 1 block x 64: exclusive scan in place
{
    int L = threadIdx.x;
    int carry = 0;
    for (int base = 0; base < NBLK_SCAN; base += 64) {
        int i = base + L;
        int v = (i < NBLK_SCAN) ? bsum[i] : 0;
        int x = v;
#pragma unroll
        for (int off = 1; off < 64; off <<= 1) {
            int y = __shfl_up(x, off);
            if (L >= off) x += y;
        }
        if (i < NBLK_SCAN) bsum[i] = x - v + carry;
        carry += __shfl(x, 63);
    }
}

__global__ __launch_bounds__(256) void scan3_k(
    const int* __restrict__ deg, const int* __restrict__ bpre, int* __restrict__ row_start)
{
    __shared__ int sm[256];
    int i = blockIdx.x * 256 + threadIdx.x;
    int v = (i < N_NODES) ? deg[i] : 0;
    sm[threadIdx.x] = v;
    __syncthreads();
    for (int off = 1; off < 256; off <<= 1) {
        int t = (threadIdx.x >= off) ? sm[threadIdx.x - off] : 0;
        __syncthreads();
        sm[threadIdx.x] += t;
        __syncthreads();
    }
    int excl = sm[threadIdx.x] - v + bpre[blockIdx.x];
    if (i <= N_NODES) row_start[i] = excl;
}

__global__ __launch_bounds__(256) void fill_k(
    const int* __restrict__ ei, const int* __restrict__ row_start,
    int* __restrict__ cursor, int* __restrict__ csr_src)
{
    int e = blockIdx.x * 256 + threadIdx.x;
    if (e >= E_TOT) return;
    int s, d;
    if (e < N_EDGES) { s = ei[e]; d = ei[N_EDGES + e]; }
    else             { s = d = e - N_EDGES; }
    int slot = row_start[d] + atomicAdd(&cursor[d], 1);
    csr_src[slot] = s;
}

// ---------------------------------------------------------------------------
// Fused layer-1 aggregation: per-edge weight computed inline (exp(lrelu(.)),
// denominator accumulated in the same loop, normalization + bias + ELU in the
// epilogue. Wave (64 lanes) per node; lane = 2 cols (float2). Unroll x4.
// ---------------------------------------------------------------------------
__global__ __launch_bounds__(256) void fagg1_k(
    const int* __restrict__ csr_src, const int* __restrict__ row_start,
    const float* __restrict__ asrc, const float* __restrict__ adst,
    const float* __restrict__ h1, const float* __restrict__ b1,
    float* __restrict__ out1)
{
    int node = blockIdx.x * 4 + (threadIdx.x >> 6);
    int L = threadIdx.x & 63;
    int h = L >> 5;                       // cols 2L,2L+1 -> head = L>>5
    int b = row_start[node], e = row_start[node + 1];
    float ad = adst[node * 2 + h];

    float2 a0 = make_float2(0.f, 0.f), a1 = a0, a2 = a0, a3 = a0;
    float d0 = 0.f, d1 = 0.f, d2 = 0.f, d3 = 0.f;

    for (int j = b; j < e; j += 4) {
        int rem = e - j;
        int s0 = csr_src[j];
        int s1 = rem > 1 ? csr_src[j + 1] : s0;
        int s2 = rem > 2 ? csr_src[j + 2] : s0;
        int s3 = rem > 3 ? csr_src[j + 3] : s0;
        float w0 = wexp(asrc[s0 * 2 + h] + ad);
        float w1 = rem > 1 ? wexp(asrc[s1 * 2 + h] + ad) : 0.f;
        float w2 = rem > 2 ? wexp(asrc[s2 * 2 + h] + ad) : 0.f;
        float w3 = rem > 3 ? wexp(asrc[s3 * 2 + h] + ad) : 0.f;
        float2 x0 = ((const float2*)(h1 + (size_t)s0 * 128))[L];
        float2 x1 = ((const float2*)(h1 + (size_t)s1 * 128))[L];
        float2 x2 = ((const float2*)(h1 + (size_t)s2 * 128))[L];
        float2 x3 = ((const float2*)(h1 + (size_t)s3 * 128))[L];
        a0.x += w0 * x0.x; a0.y += w0 * x0.y; d0 += w0;
        a1.x += w1 * x1.x; a1.y += w1 * x1.y; d1 += w1;
        a2.x += w2 * x2.x; a2.y += w2 * x2.y; d2 += w2;
        a3.x += w3 * x3.x; a3.y += w3 * x3.y; d3 += w3;
    }

    float inv = 1.f / (((d0 + d1) + (d2 + d3)) + 1e-16f);
    float2 bb = ((const float2*)b1)[L];
    float vx = (a0.x + a1.x + a2.x + a3.x) * inv + bb.x;
    float vy = (a0.y + a1.y + a2.y + a3.y) * inv + bb.y;
    vx = vx > 0.f ? vx : expm1f(vx);
    vy = vy > 0.f ? vy : expm1f(vy);
    ((float2*)(out1 + (size_t)node * 128))[L] = make_float2(vx, vy);
}

// ---------------------------------------------------------------------------
// GEMM2: h2[N,48pad] = in[N,128] @ W2[128,40]; fused alpha2 reductions.
// h2 rows padded to 48 floats (192B = 3 aligned cache lines).
// ---------------------------------------------------------------------------
__global__ __launch_bounds__(256) void gemm2_k(
    const float* __restrict__ in, const float* __restrict__ W2,
    const float* __restrict__ as2, const float* __restrict__ ad2,
    float* __restrict__ h2, float* __restrict__ asrc, float* __restrict__ adst)
{
    __shared__ float WsT[40 * 132];
    __shared__ float as_s[40], ad_s[40];
    const int t = threadIdx.x;
    for (int i = t; i < 5120; i += 256) {
        int k = i / 40, c = i - k * 40;
        WsT[c * 132 + k] = W2[i];
    }
    if (t < 40) { as_s[t] = as2[t]; ad_s[t] = ad2[t]; }
    __syncthreads();

    const int wv = t >> 6, L = t & 63;
    const int base = blockIdx.x * 32 + wv * 8;
    for (int ni = 0; ni < 8; ++ni) {
        int n = base + ni;
        const float4* row4 = (const float4*)(in + (size_t)n * 128);
        float a = 0.f;
        if (L < 40) {
            const float4* wrow = (const float4*)&WsT[L * 132];
            float4 a4 = make_float4(0.f, 0.f, 0.f, 0.f);
            for (int k4 = 0; k4 < 32; ++k4) {
                float4 xv = row4[k4];
                float4 wvv = wrow[k4];
                a4.x += xv.x * wvv.x; a4.y += xv.y * wvv.y;
                a4.z += xv.z * wvv.z; a4.w += xv.w * wvv.w;
            }
            a = (a4.x + a4.y) + (a4.z + a4.w);
            h2[(size_t)n * 48 + L] = a;
        }
        float ps = (L < 40) ? a * as_s[L] : 0.f;
        float pd = (L < 40) ? a * ad_s[L] : 0.f;
#pragma unroll
        for (int off = 32; off; off >>= 1) {
            ps += __shfl_xor(ps, off);
            pd += __shfl_xor(pd, off);
        }
        if (L == 0) { asrc[n] = ps; adst[n] = pd; }
    }
}

// ---------------------------------------------------------------------------
// Fused layer-2 aggregation + softmax denom + bias + log_softmax.
// Wave per node, lanes 0..39 = cols. Unroll x4.
// ---------------------------------------------------------------------------
__global__ __launch_bounds__(256) void fagg2_k(
    const int* __restrict__ csr_src, const int* __restrict__ row_start,
    const float* __restrict__ asrc, const float* __restrict__ adst,
    const float* __restrict__ h2, const float* __restrict__ b2,
    float* __restrict__ out)
{
    int node = blockIdx.x * 4 + (threadIdx.x >> 6);
    int L = threadIdx.x & 63;
    bool act = L < 40;
    int col = act ? L : 0;
    int b = row_start[node], e = row_start[node + 1];
    float ad = adst[node];

    float a0 = 0.f, a1 = 0.f, a2 = 0.f, a3 = 0.f;
    float d0 = 0.f, d1 = 0.f, d2 = 0.f, d3 = 0.f;

    for (int j = b; j < e; j += 4) {
        int rem = e - j;
        int s0 = csr_src[j];
        int s1 = rem > 1 ? csr_src[j + 1] : s0;
        int s2 = rem > 2 ? csr_src[j + 2] : s0;
        int s3 = rem > 3 ? csr_src[j + 3] : s0;
        float w0 = wexp(asrc[s0] + ad);
        float w1 = rem > 1 ? wexp(asrc[s1] + ad) : 0.f;
        float w2 = rem > 2 ? wexp(asrc[s2] + ad) : 0.f;
        float w3 = rem > 3 ? wexp(asrc[s3] + ad) : 0.f;
        float x0 = h2[(size_t)s0 * 48 + col];
        float x1 = h2[(size_t)s1 * 48 + col];
        float x2 = h2[(size_t)s2 * 48 + col];
        float x3 = h2[(size_t)s3 * 48 + col];
        a0 += w0 * x0; d0 += w0;
        a1 += w1 * x1; d1 += w1;
        a2 += w2 * x2; d2 += w2;
        a3 += w3 * x3; d3 += w3;
    }

    float den = (d0 + d1) + (d2 + d3);
    float acc = (a0 + a1) + (a2 + a3);
    float v = act ? acc / (den + 1e-16f) + b2[L] : -1e30f;
    float mx = v;
#pragma unroll
    for (int off = 32; off; off >>= 1) mx = fmaxf(mx, __shfl_xor(mx, off));
    float ex = act ? __expf(v - mx) : 0.f;
#pragma unroll
    for (int off = 32; off; off >>= 1) ex += __shfl_xor(ex, off);
    if (act) out[(size_t)node * 40 + L] = v - mx - logf(ex);
}

// ---------------------------------------------------------------------------
extern "C" void kernel_launch(void* const* d_in, const int* in_sizes, int n_in,
                              void* d_out, int out_size, void* d_ws, size_t ws_size,
                              hipStream_t stream)
{
    const float* x   = (const float*)d_in[0];
    const int*   ei  = (const int*)d_in[1];
    const float* W1  = (const float*)d_in[2];
    const float* as1 = (const float*)d_in[3];
    const float* ad1 = (const float*)d_in[4];
    const float* b1  = (const float*)d_in[5];
    const float* W2  = (const float*)d_in[6];
    const float* as2 = (const float*)d_in[7];
    const float* ad2 = (const float*)d_in[8];
    const float* b2  = (const float*)d_in[9];
    float* out = (float*)d_out;

    float* ws = (float*)d_ws;
    // workspace layout (4B units); total ~28.3M = 113 MB
    float* h1    = ws;                       // N*128 ; reused as h2 (N*48) in layer 2
    float* out1  = ws + 12800000;            // N*128
    float* asrc1 = ws + 25600000;            // 2N
    float* adst1 = ws + 25800000;            // 2N
    float* asrc2 = ws + 26000000;            // N
    float* adst2 = ws + 26100000;            // N
    int* deg       = (int*)(ws + 26200000);  // N
    int* cursor    = (int*)(ws + 26300000);  // N
    int* row_start = (int*)(ws + 26400000);  // N+1
    int* bsum      = (int*)(ws + 26550000);  // NBLK_SCAN
    int* csr_src   = (int*)(ws + 26600000);  // E_TOT

    // zero deg + cursor (contiguous, 200k ints)
    hipMemsetAsync(deg, 0, (size_t)200000 * sizeof(int), stream);

    // CSR build (shared by both layers)
    count_k<<<6641, 256, 0, stream>>>(ei, deg);
    scan1_k<<<NBLK_SCAN, 256, 0, stream>>>(deg, bsum);
    scan2_k<<<1, 64, 0, stream>>>(bsum);
    scan3_k<<<NBLK_SCAN, 256, 0, stream>>>(deg, bsum, row_start);
    fill_k<<<6641, 256, 0, stream>>>(ei, row_start, cursor, csr_src);

    // layer 1
    gemm1_k<<<3125, 256, 0, stream>>>(x, W1, as1, ad1, h1, asrc1, adst1);
    fagg1_k<<<25000, 256, 0, stream>>>(csr_src, row_start, asrc1, adst1, h1, b1, out1);

    // layer 2 (h2 reuses h1 region, stride 48)
    float* h2 = h1;
    gemm2_k<<<3125, 256, 0, stream>>>(out1, W2, as2, ad2, h2, asrc2, adst2);
    fagg2_k<<<25000, 256, 0, stream>>>(csr_src, row_start, asrc2, adst2, h2, b2, out);
}

// Round 4
// 534.585 us; speedup vs baseline: 2.7810x; 1.1900x over previous
//
#include <hip/hip_runtime.h>
#include <hip/hip_fp16.h>
#include <math.h>

#define N_NODES 100000
#define N_EDGES 1600000
#define E_TOT   (N_EDGES + N_NODES)
#define NBLK_SCAN 391   // ceil(N_NODES/256)

__device__ __forceinline__ float wexp(float v) {
    v = v > 0.f ? v : 0.2f * v;
    return __expf(v);
}

// ---------------------------------------------------------------------------
// GEMM1: h1[N,128] = x[N,128] @ W1[128,128]; fused alpha_src/alpha_dst.
// Alphas computed in fp32; h1 stored as fp16 (halves the fagg1 gather bytes).
// W1 staged in LDS (64KB). 8 teams of 32 lanes; team = 4 nodes; lane = 4 cols.
// ---------------------------------------------------------------------------
__global__ __launch_bounds__(256) void gemm1_k(
    const float* __restrict__ x, const float* __restrict__ W1,
    const float* __restrict__ as1, const float* __restrict__ ad1,
    __half* __restrict__ h1h, float* __restrict__ asrc, float* __restrict__ adst)
{
    __shared__ float4 Ws[128 * 32];
    const int t = threadIdx.x;
    const float4* W4 = (const float4*)W1;
#pragma unroll
    for (int i = 0; i < 16; ++i) Ws[t + i * 256] = W4[t + i * 256];
    __syncthreads();

    const int team = t >> 5;
    const int L    = t & 31;
    const int node0 = blockIdx.x * 32 + team * 4;

    const float* xr0 = x + (size_t)(node0 + 0) * 128;
    const float* xr1 = x + (size_t)(node0 + 1) * 128;
    const float* xr2 = x + (size_t)(node0 + 2) * 128;
    const float* xr3 = x + (size_t)(node0 + 3) * 128;

    float4 accs[4];
#pragma unroll
    for (int i = 0; i < 4; ++i) accs[i] = make_float4(0.f, 0.f, 0.f, 0.f);

    for (int k = 0; k < 128; ++k) {
        float4 w = Ws[k * 32 + L];
        float a = xr0[k], b = xr1[k], c = xr2[k], d = xr3[k];
        accs[0].x += w.x * a; accs[0].y += w.y * a; accs[0].z += w.z * a; accs[0].w += w.w * a;
        accs[1].x += w.x * b; accs[1].y += w.y * b; accs[1].z += w.z * b; accs[1].w += w.w * b;
        accs[2].x += w.x * c; accs[2].y += w.y * c; accs[2].z += w.z * c; accs[2].w += w.w * c;
        accs[3].x += w.x * d; accs[3].y += w.y * d; accs[3].z += w.z * d; accs[3].w += w.w * d;
    }

    float4 as4 = ((const float4*)as1)[L];
    float4 ad4 = ((const float4*)ad1)[L];
#pragma unroll
    for (int nt = 0; nt < 4; ++nt) {
        int node = node0 + nt;
        __half2* row = (__half2*)(h1h + (size_t)node * 128);
        row[2 * L]     = __floats2half2_rn(accs[nt].x, accs[nt].y);
        row[2 * L + 1] = __floats2half2_rn(accs[nt].z, accs[nt].w);
        float ps = accs[nt].x * as4.x + accs[nt].y * as4.y + accs[nt].z * as4.z + accs[nt].w * as4.w;
        float pd = accs[nt].x * ad4.x + accs[nt].y * ad4.y + accs[nt].z * ad4.z + accs[nt].w * ad4.w;
#pragma unroll
        for (int off = 1; off < 16; off <<= 1) {
            ps += __shfl_xor(ps, off);
            pd += __shfl_xor(pd, off);
        }
        if ((L & 15) == 0) {
            int h = L >> 4;
            asrc[node * 2 + h] = ps;
            adst[node * 2 + h] = pd;
        }
    }
}

// ---------------------------------------------------------------------------
// CSR build: count -> scan (3 kernels, deterministic) -> fill
// ---------------------------------------------------------------------------
__global__ __launch_bounds__(256) void count_k(const int* __restrict__ ei, int* __restrict__ deg)
{
    int e = blockIdx.x * 256 + threadIdx.x;
    if (e >= E_TOT) return;
    int d = (e < N_EDGES) ? ei[N_EDGES + e] : e - N_EDGES;
    atomicAdd(&deg[d], 1);
}

__global__ __launch_bounds__(256) void scan1_k(const int* __restrict__ deg, int* __restrict__ bsum)
{
    __shared__ int sm[256];
    int i = blockIdx.x * 256 + threadIdx.x;
    sm[threadIdx.x] = (i < N_NODES) ? deg[i] : 0;
    __syncthreads();
    for (int off = 128; off; off >>= 1) {
        if (threadIdx.x < off) sm[threadIdx.x] += sm[threadIdx.x + off];
        __syncthreads();
    }
    if (threadIdx.x == 0) bsum[blockIdx.x] = sm[0];
}

__global__ void scan2_k(int* __restrict__ bsum)   // 1 block x 64: exclusive scan in place
{
    int L = threadIdx.x;
    int carry = 0;
    for (int base = 0; base < NBLK_SCAN; base += 64) {
        int i = base + L;
        int v = (i < NBLK_SCAN) ? bsum[i] : 0;
        int x = v;
#pragma unroll
        for (int off = 1; off < 64; off <<= 1) {
            int y = __shfl_up(x, off);
            if (L >= off) x += y;
        }
        if (i < NBLK_SCAN) bsum[i] = x - v + carry;
        carry += __shfl(x, 63);
    }
}

__global__ __launch_bounds__(256) void scan3_k(
    const int* __restrict__ deg, const int* __restrict__ bpre, int* __restrict__ row_start)
{
    __shared__ int sm[256];
    int i = blockIdx.x * 256 + threadIdx.x;
    int v = (i < N_NODES) ? deg[i] : 0;
    sm[threadIdx.x] = v;
    __syncthreads();
    for (int off = 1; off < 256; off <<= 1) {
        int t = (threadIdx.x >= off) ? sm[threadIdx.x - off] : 0;
        __syncthreads();
        sm[threadIdx.x] += t;
        __syncthreads();
    }
    int excl = sm[threadIdx.x] - v + bpre[blockIdx.x];
    if (i <= N_NODES) row_start[i] = excl;
}

__global__ __launch_bounds__(256) void fill_k(
    const int* __restrict__ ei, const int* __restrict__ row_start,
    int* __restrict__ cursor, int* __restrict__ csr_src)
{
    int e = blockIdx.x * 256 + threadIdx.x;
    if (e >= E_TOT) return;
    int s, d;
    if (e < N_EDGES) { s = ei[e]; d = ei[N_EDGES + e]; }
    else             { s = d = e - N_EDGES; }
    int slot = row_start[d] + atomicAdd(&cursor[d], 1);
    csr_src[slot] = s;
}

// ---------------------------------------------------------------------------
// Fused layer-1 aggregation: inline exp(lrelu(.)) weights + denominator in the
// same loop; normalize + bias + ELU in the epilogue. Wave per node;
// lane = 2 cols (half2 gather). Unroll x4 with branch-free main body + tail.
// ---------------------------------------------------------------------------
__global__ __launch_bounds__(256) void fagg1_k(
    const int* __restrict__ csr_src, const int* __restrict__ row_start,
    const float* __restrict__ asrc, const float* __restrict__ adst,
    const __half* __restrict__ h1h, const float* __restrict__ b1,
    float* __restrict__ out1)
{
    int node = blockIdx.x * 4 + (threadIdx.x >> 6);
    int L = threadIdx.x & 63;
    int h = L >> 5;                       // cols 2L,2L+1 -> head = L>>5
    int b = row_start[node], e = row_start[node + 1];
    const float* as_h = asrc + h;         // index with s*2
    float ad = adst[node * 2 + h];
    const __half2* H = (const __half2*)h1h;

    float2 a0 = make_float2(0.f, 0.f), a1 = a0, a2 = a0, a3 = a0;
    float d0 = 0.f, d1 = 0.f, d2 = 0.f, d3 = 0.f;

    int j = b;
    for (; j + 3 < e; j += 4) {
        int s0 = csr_src[j], s1 = csr_src[j + 1], s2 = csr_src[j + 2], s3 = csr_src[j + 3];
        float w0 = wexp(as_h[s0 * 2] + ad);
        float w1 = wexp(as_h[s1 * 2] + ad);
        float w2 = wexp(as_h[s2 * 2] + ad);
        float w3 = wexp(as_h[s3 * 2] + ad);
        float2 x0 = __half22float2(H[(size_t)s0 * 64 + L]);
        float2 x1 = __half22float2(H[(size_t)s1 * 64 + L]);
        float2 x2 = __half22float2(H[(size_t)s2 * 64 + L]);
        float2 x3 = __half22float2(H[(size_t)s3 * 64 + L]);
        a0.x += w0 * x0.x; a0.y += w0 * x0.y; d0 += w0;
        a1.x += w1 * x1.x; a1.y += w1 * x1.y; d1 += w1;
        a2.x += w2 * x2.x; a2.y += w2 * x2.y; d2 += w2;
        a3.x += w3 * x3.x; a3.y += w3 * x3.y; d3 += w3;
    }
    for (; j < e; ++j) {
        int s = csr_src[j];
        float w = wexp(as_h[s * 2] + ad);
        float2 xv = __half22float2(H[(size_t)s * 64 + L]);
        a0.x += w * xv.x; a0.y += w * xv.y; d0 += w;
    }

    float inv = 1.f / (((d0 + d1) + (d2 + d3)) + 1e-16f);
    float2 bb = ((const float2*)b1)[L];
    float vx = (a0.x + a1.x + a2.x + a3.x) * inv + bb.x;
    float vy = (a0.y + a1.y + a2.y + a3.y) * inv + bb.y;
    vx = vx > 0.f ? vx : expm1f(vx);
    vy = vy > 0.f ? vy : expm1f(vy);
    ((float2*)(out1 + (size_t)node * 128))[L] = make_float2(vx, vy);
}

// ---------------------------------------------------------------------------
// GEMM2: h2[N,64pad fp16] = in[N,128] @ W2[128,40]; fused alpha2 reductions.
// Row = 64 halves = exactly one 128B cache line.
// ---------------------------------------------------------------------------
__global__ __launch_bounds__(256) void gemm2_k(
    const float* __restrict__ in, const float* __restrict__ W2,
    const float* __restrict__ as2, const float* __restrict__ ad2,
    __half* __restrict__ h2h, float* __restrict__ asrc, float* __restrict__ adst)
{
    __shared__ float WsT[40 * 132];
    __shared__ float as_s[40], ad_s[40];
    const int t = threadIdx.x;
    for (int i = t; i < 5120; i += 256) {
        int k = i / 40, c = i - k * 40;
        WsT[c * 132 + k] = W2[i];
    }
    if (t < 40) { as_s[t] = as2[t]; ad_s[t] = ad2[t]; }
    __syncthreads();

    const int wv = t >> 6, L = t & 63;
    const int base = blockIdx.x * 32 + wv * 8;
    for (int ni = 0; ni < 8; ++ni) {
        int n = base + ni;
        const float4* row4 = (const float4*)(in + (size_t)n * 128);
        float a = 0.f;
        if (L < 40) {
            const float4* wrow = (const float4*)&WsT[L * 132];
            float4 a4 = make_float4(0.f, 0.f, 0.f, 0.f);
            for (int k4 = 0; k4 < 32; ++k4) {
                float4 xv = row4[k4];
                float4 wvv = wrow[k4];
                a4.x += xv.x * wvv.x; a4.y += xv.y * wvv.y;
                a4.z += xv.z * wvv.z; a4.w += xv.w * wvv.w;
            }
            a = (a4.x + a4.y) + (a4.z + a4.w);
            h2h[(size_t)n * 64 + L] = __float2half_rn(a);
        }
        float ps = (L < 40) ? a * as_s[L] : 0.f;
        float pd = (L < 40) ? a * ad_s[L] : 0.f;
#pragma unroll
        for (int off = 32; off; off >>= 1) {
            ps += __shfl_xor(ps, off);
            pd += __shfl_xor(pd, off);
        }
        if (L == 0) { asrc[n] = ps; adst[n] = pd; }
    }
}

// ---------------------------------------------------------------------------
// Fused layer-2 aggregation + softmax denom + bias + log_softmax.
// Wave per node, lanes 0..39 = cols. Unroll x4, branch-free body + tail.
// ---------------------------------------------------------------------------
__global__ __launch_bounds__(256) void fagg2_k(
    const int* __restrict__ csr_src, const int* __restrict__ row_start,
    const float* __restrict__ asrc, const float* __restrict__ adst,
    const __half* __restrict__ h2h, const float* __restrict__ b2,
    float* __restrict__ out)
{
    int node = blockIdx.x * 4 + (threadIdx.x >> 6);
    int L = threadIdx.x & 63;
    bool act = L < 40;
    int col = act ? L : 0;
    int b = row_start[node], e = row_start[node + 1];
    float ad = adst[node];

    float a0 = 0.f, a1 = 0.f, a2 = 0.f, a3 = 0.f;
    float d0 = 0.f, d1 = 0.f, d2 = 0.f, d3 = 0.f;

    int j = b;
    for (; j + 3 < e; j += 4) {
        int s0 = csr_src[j], s1 = csr_src[j + 1], s2 = csr_src[j + 2], s3 = csr_src[j + 3];
        float w0 = wexp(asrc[s0] + ad);
        float w1 = wexp(asrc[s1] + ad);
        float w2 = wexp(asrc[s2] + ad);
        float w3 = wexp(asrc[s3] + ad);
        float x0 = __half2float(h2h[(size_t)s0 * 64 + col]);
        float x1 = __half2float(h2h[(size_t)s1 * 64 + col]);
        float x2 = __half2float(h2h[(size_t)s2 * 64 + col]);
        float x3 = __half2float(h2h[(size_t)s3 * 64 + col]);
        a0 += w0 * x0; d0 += w0;
        a1 += w1 * x1; d1 += w1;
        a2 += w2 * x2; d2 += w2;
        a3 += w3 * x3; d3 += w3;
    }
    for (; j < e; ++j) {
        int s = csr_src[j];
        float w = wexp(asrc[s] + ad);
        float xv = __half2float(h2h[(size_t)s * 64 + col]);
        a0 += w * xv; d0 += w;
    }

    float den = (d0 + d1) + (d2 + d3);
    float acc = (a0 + a1) + (a2 + a3);
    float v = act ? acc / (den + 1e-16f) + b2[L] : -1e30f;
    float mx = v;
#pragma unroll
    for (int off = 32; off; off >>= 1) mx = fmaxf(mx, __shfl_xor(mx, off));
    float ex = act ? __expf(v - mx) : 0.f;
#pragma unroll
    for (int off = 32; off; off >>= 1) ex += __shfl_xor(ex, off);
    if (act) out[(size_t)node * 40 + L] = v - mx - logf(ex);
}

// ---------------------------------------------------------------------------
extern "C" void kernel_launch(void* const* d_in, const int* in_sizes, int n_in,
                              void* d_out, int out_size, void* d_ws, size_t ws_size,
                              hipStream_t stream)
{
    const float* x   = (const float*)d_in[0];
    const int*   ei  = (const int*)d_in[1];
    const float* W1  = (const float*)d_in[2];
    const float* as1 = (const float*)d_in[3];
    const float* ad1 = (const float*)d_in[4];
    const float* b1  = (const float*)d_in[5];
    const float* W2  = (const float*)d_in[6];
    const float* as2 = (const float*)d_in[7];
    const float* ad2 = (const float*)d_in[8];
    const float* b2  = (const float*)d_in[9];
    float* out = (float*)d_out;

    float* ws = (float*)d_ws;
    // workspace layout (4B units); total ~21.9M = 87.6 MB
    __half* h1h  = (__half*)ws;              // N*128 halves = 6.4M floats; reused as h2h (N*64 halves)
    float* out1  = ws + 6400000;             // N*128
    float* asrc1 = ws + 19200000;            // 2N
    float* adst1 = ws + 19400000;            // 2N
    float* asrc2 = ws + 19600000;            // N
    float* adst2 = ws + 19700000;            // N
    int* deg       = (int*)(ws + 19800000);  // N
    int* cursor    = (int*)(ws + 19900000);  // N
    int* row_start = (int*)(ws + 20000000);  // N+1
    int* bsum      = (int*)(ws + 20150000);  // NBLK_SCAN
    int* csr_src   = (int*)(ws + 20200000);  // E_TOT

    // zero deg + cursor (contiguous, 200k ints)
    hipMemsetAsync(deg, 0, (size_t)200000 * sizeof(int), stream);

    // CSR build (shared by both layers)
    count_k<<<6641, 256, 0, stream>>>(ei, deg);
    scan1_k<<<NBLK_SCAN, 256, 0, stream>>>(deg, bsum);
    scan2_k<<<1, 64, 0, stream>>>(bsum);
    scan3_k<<<NBLK_SCAN, 256, 0, stream>>>(deg, bsum, row_start);
    fill_k<<<6641, 256, 0, stream>>>(ei, row_start, cursor, csr_src);

    // layer 1
    gemm1_k<<<3125, 256, 0, stream>>>(x, W1, as1, ad1, h1h, asrc1, adst1);
    fagg1_k<<<25000, 256, 0, stream>>>(csr_src, row_start, asrc1, adst1, h1h, b1, out1);

    // layer 2 (h2h reuses h1h region, stride 64 halves = one 128B line)
    __half* h2h = h1h;
    gemm2_k<<<3125, 256, 0, stream>>>(out1, W2, as2, ad2, h2h, asrc2, adst2);
    fagg2_k<<<25000, 256, 0, stream>>>(csr_src, row_start, asrc2, adst2, h2h, b2, out);
}

// Round 5
// 391.597 us; speedup vs baseline: 3.7964x; 1.3651x over previous
//
#include <hip/hip_runtime.h>
#include <hip/hip_fp16.h>
#include <math.h>

#define N_NODES 100000
#define N_EDGES 1600000
#define E_TOT   (N_EDGES + N_NODES)

// bucketed CSR build
#define NB     512          // buckets
#define NPB    196          // dst-nodes per bucket (512*196 = 100352 >= N)
#define BCAP   4096         // capacity per bucket (mean 3332, +13 sigma)
#define BIN_CH 4096         // edges per bin_k workgroup
#define NBIN_WG ((E_TOT + BIN_CH - 1) / BIN_CH)

__device__ __forceinline__ float wexp(float v) {
    v = v > 0.f ? v : 0.2f * v;
    return __expf(v);
}

// ---------------------------------------------------------------------------
// GEMM1: h1[N,128] = x[N,128] @ W1[128,128]; fused alpha_src/alpha_dst.
// Alphas in fp32; h1 stored fp16. W1 staged in LDS (64KB).
// ---------------------------------------------------------------------------
__global__ __launch_bounds__(256) void gemm1_k(
    const float* __restrict__ x, const float* __restrict__ W1,
    const float* __restrict__ as1, const float* __restrict__ ad1,
    __half* __restrict__ h1h, float* __restrict__ asrc, float* __restrict__ adst)
{
    __shared__ float4 Ws[128 * 32];
    const int t = threadIdx.x;
    const float4* W4 = (const float4*)W1;
#pragma unroll
    for (int i = 0; i < 16; ++i) Ws[t + i * 256] = W4[t + i * 256];
    __syncthreads();

    const int team = t >> 5;
    const int L    = t & 31;
    const int node0 = blockIdx.x * 32 + team * 4;

    const float* xr0 = x + (size_t)(node0 + 0) * 128;
    const float* xr1 = x + (size_t)(node0 + 1) * 128;
    const float* xr2 = x + (size_t)(node0 + 2) * 128;
    const float* xr3 = x + (size_t)(node0 + 3) * 128;

    float4 accs[4];
#pragma unroll
    for (int i = 0; i < 4; ++i) accs[i] = make_float4(0.f, 0.f, 0.f, 0.f);

    for (int k = 0; k < 128; ++k) {
        float4 w = Ws[k * 32 + L];
        float a = xr0[k], b = xr1[k], c = xr2[k], d = xr3[k];
        accs[0].x += w.x * a; accs[0].y += w.y * a; accs[0].z += w.z * a; accs[0].w += w.w * a;
        accs[1].x += w.x * b; accs[1].y += w.y * b; accs[1].z += w.z * b; accs[1].w += w.w * b;
        accs[2].x += w.x * c; accs[2].y += w.y * c; accs[2].z += w.z * c; accs[2].w += w.w * c;
        accs[3].x += w.x * d; accs[3].y += w.y * d; accs[3].z += w.z * d; accs[3].w += w.w * d;
    }

    float4 as4 = ((const float4*)as1)[L];
    float4 ad4 = ((const float4*)ad1)[L];
#pragma unroll
    for (int nt = 0; nt < 4; ++nt) {
        int node = node0 + nt;
        __half2* row = (__half2*)(h1h + (size_t)node * 128);
        row[2 * L]     = __floats2half2_rn(accs[nt].x, accs[nt].y);
        row[2 * L + 1] = __floats2half2_rn(accs[nt].z, accs[nt].w);
        float ps = accs[nt].x * as4.x + accs[nt].y * as4.y + accs[nt].z * as4.z + accs[nt].w * as4.w;
        float pd = accs[nt].x * ad4.x + accs[nt].y * ad4.y + accs[nt].z * ad4.z + accs[nt].w * ad4.w;
#pragma unroll
        for (int off = 1; off < 16; off <<= 1) {
            ps += __shfl_xor(ps, off);
            pd += __shfl_xor(pd, off);
        }
        if ((L & 15) == 0) {
            int h = L >> 4;
            asrc[node * 2 + h] = ps;
            adst[node * 2 + h] = pd;
        }
    }
}

// ---------------------------------------------------------------------------
// CSR build, phase 1: bin edges by dst bucket. LDS-aggregated histogram ->
// ~1 global atomic per (bucket,wg); packed records (d_local<<17)|src.
// ---------------------------------------------------------------------------
__global__ __launch_bounds__(256) void bin_k(
    const int* __restrict__ ei, int* __restrict__ bcur, unsigned* __restrict__ bdata)
{
    __shared__ int hist[NB];
    __shared__ int base[NB];
    const int t = threadIdx.x;
    const int e0 = blockIdx.x * BIN_CH;
    const int n = min(BIN_CH, E_TOT - e0);

    for (int b = t; b < NB; b += 256) hist[b] = 0;
    __syncthreads();

    for (int i = t; i < n; i += 256) {
        int e = e0 + i;
        int d = (e < N_EDGES) ? ei[N_EDGES + e] : e - N_EDGES;
        atomicAdd(&hist[d / NPB], 1);
    }
    __syncthreads();

    for (int b = t; b < NB; b += 256) {
        int c = hist[b];
        base[b] = c ? atomicAdd(&bcur[b], c) : 0;
        hist[b] = 0;      // reuse as local cursor
    }
    __syncthreads();

    for (int i = t; i < n; i += 256) {
        int e = e0 + i;
        int s, d;
        if (e < N_EDGES) { s = ei[e]; d = ei[N_EDGES + e]; }
        else             { s = d = e - N_EDGES; }
        int b  = d / NPB;
        int dl = d - b * NPB;
        int pos = base[b] + atomicAdd(&hist[b], 1);
        if (pos < BCAP)
            bdata[(size_t)b * BCAP + pos] = (unsigned)s | ((unsigned)dl << 17);
    }
}

// ---------------------------------------------------------------------------
// CSR build, phase 2a: exclusive scan of bucket counts (1 wg x 512 threads).
// ---------------------------------------------------------------------------
__global__ __launch_bounds__(512) void scanb_k(
    const int* __restrict__ bcur, int* __restrict__ bbase)
{
    __shared__ int a[NB], b_[NB];
    int t = threadIdx.x;
    int v = bcur[t];
    a[t] = v;
    __syncthreads();
    int* src = a; int* dst = b_;
    for (int off = 1; off < NB; off <<= 1) {
        dst[t] = (t >= off) ? src[t - off] + src[t] : src[t];
        __syncthreads();
        int* tmp = src; src = dst; dst = tmp;
    }
    bbase[t] = src[t] - v;   // exclusive
}

// ---------------------------------------------------------------------------
// CSR build, phase 2b: wg per bucket. LDS-stage records, local hist + scan,
// write row_start (coalesced) and place csr_src into the bucket's exclusive
// contiguous region (L2-resident, merged writebacks).
// ---------------------------------------------------------------------------
__global__ __launch_bounds__(256) void build_k(
    const unsigned* __restrict__ bdata, const int* __restrict__ bcur,
    const int* __restrict__ bbase, int* __restrict__ row_start,
    int* __restrict__ csr_src)
{
    __shared__ unsigned rec[BCAP];     // 16 KB
    __shared__ int hist[256];
    __shared__ int excl[NPB];
    __shared__ int lcur[NPB];
    const int t = threadIdx.x;
    const int b = blockIdx.x;
    const int cnt = min(bcur[b], BCAP);
    const int bb = bbase[b];

    hist[t] = 0;
    if (t < NPB) lcur[t] = 0;
    __syncthreads();

    for (int i = t; i < cnt; i += 256) {
        unsigned r = bdata[(size_t)b * BCAP + i];
        rec[i] = r;
        atomicAdd(&hist[r >> 17], 1);
    }
    __syncthreads();

    int v = hist[t];
    __syncthreads();
    for (int off = 1; off < 256; off <<= 1) {
        int y = (t >= off) ? hist[t - off] : 0;
        __syncthreads();
        hist[t] += y;
        __syncthreads();
    }
    if (t < NPB) excl[t] = hist[t] - v;
    __syncthreads();

    int node = b * NPB + t;
    if (t < NPB && node <= N_NODES) row_start[node] = bb + excl[t];

    for (int i = t; i < cnt; i += 256) {
        unsigned r = rec[i];
        int dl = r >> 17;
        int s  = r & 0x1FFFF;
        int slot = atomicAdd(&lcur[dl], 1);
        csr_src[bb + excl[dl] + slot] = s;
    }
}

// ---------------------------------------------------------------------------
// Fused layer-1 aggregation (unchanged from round 4).
// ---------------------------------------------------------------------------
__global__ __launch_bounds__(256) void fagg1_k(
    const int* __restrict__ csr_src, const int* __restrict__ row_start,
    const float* __restrict__ asrc, const float* __restrict__ adst,
    const __half* __restrict__ h1h, const float* __restrict__ b1,
    float* __restrict__ out1)
{
    int node = blockIdx.x * 4 + (threadIdx.x >> 6);
    int L = threadIdx.x & 63;
    int h = L >> 5;
    int b = row_start[node], e = row_start[node + 1];
    const float* as_h = asrc + h;
    float ad = adst[node * 2 + h];
    const __half2* H = (const __half2*)h1h;

    float2 a0 = make_float2(0.f, 0.f), a1 = a0, a2 = a0, a3 = a0;
    float d0 = 0.f, d1 = 0.f, d2 = 0.f, d3 = 0.f;

    int j = b;
    for (; j + 3 < e; j += 4) {
        int s0 = csr_src[j], s1 = csr_src[j + 1], s2 = csr_src[j + 2], s3 = csr_src[j + 3];
        float w0 = wexp(as_h[s0 * 2] + ad);
        float w1 = wexp(as_h[s1 * 2] + ad);
        float w2 = wexp(as_h[s2 * 2] + ad);
        float w3 = wexp(as_h[s3 * 2] + ad);
        float2 x0 = __half22float2(H[(size_t)s0 * 64 + L]);
        float2 x1 = __half22float2(H[(size_t)s1 * 64 + L]);
        float2 x2 = __half22float2(H[(size_t)s2 * 64 + L]);
        float2 x3 = __half22float2(H[(size_t)s3 * 64 + L]);
        a0.x += w0 * x0.x; a0.y += w0 * x0.y; d0 += w0;
        a1.x += w1 * x1.x; a1.y += w1 * x1.y; d1 += w1;
        a2.x += w2 * x2.x; a2.y += w2 * x2.y; d2 += w2;
        a3.x += w3 * x3.x; a3.y += w3 * x3.y; d3 += w3;
    }
    for (; j < e; ++j) {
        int s = csr_src[j];
        float w = wexp(as_h[s * 2] + ad);
        float2 xv = __half22float2(H[(size_t)s * 64 + L]);
        a0.x += w * xv.x; a0.y += w * xv.y; d0 += w;
    }

    float inv = 1.f / (((d0 + d1) + (d2 + d3)) + 1e-16f);
    float2 bb = ((const float2*)b1)[L];
    float vx = (a0.x + a1.x + a2.x + a3.x) * inv + bb.x;
    float vy = (a0.y + a1.y + a2.y + a3.y) * inv + bb.y;
    vx = vx > 0.f ? vx : expm1f(vx);
    vy = vy > 0.f ? vy : expm1f(vy);
    ((float2*)(out1 + (size_t)node * 128))[L] = make_float2(vx, vy);
}

// ---------------------------------------------------------------------------
// GEMM2: h2[N,64pad fp16] = in[N,128] @ W2[128,40]; fused alpha2 reductions.
// ---------------------------------------------------------------------------
__global__ __launch_bounds__(256) void gemm2_k(
    const float* __restrict__ in, const float* __restrict__ W2,
    const float* __restrict__ as2, const float* __restrict__ ad2,
    __half* __restrict__ h2h, float* __restrict__ asrc, float* __restrict__ adst)
{
    __shared__ float WsT[40 * 132];
    __shared__ float as_s[40], ad_s[40];
    const int t = threadIdx.x;
    for (int i = t; i < 5120; i += 256) {
        int k = i / 40, c = i - k * 40;
        WsT[c * 132 + k] = W2[i];
    }
    if (t < 40) { as_s[t] = as2[t]; ad_s[t] = ad2[t]; }
    __syncthreads();

    const int wv = t >> 6, L = t & 63;
    const int base = blockIdx.x * 32 + wv * 8;
    for (int ni = 0; ni < 8; ++ni) {
        int n = base + ni;
        const float4* row4 = (const float4*)(in + (size_t)n * 128);
        float a = 0.f;
        if (L < 40) {
            const float4* wrow = (const float4*)&WsT[L * 132];
            float4 a4 = make_float4(0.f, 0.f, 0.f, 0.f);
            for (int k4 = 0; k4 < 32; ++k4) {
                float4 xv = row4[k4];
                float4 wvv = wrow[k4];
                a4.x += xv.x * wvv.x; a4.y += xv.y * wvv.y;
                a4.z += xv.z * wvv.z; a4.w += xv.w * wvv.w;
            }
            a = (a4.x + a4.y) + (a4.z + a4.w);
            h2h[(size_t)n * 64 + L] = __float2half_rn(a);
        }
        float ps = (L < 40) ? a * as_s[L] : 0.f;
        float pd = (L < 40) ? a * ad_s[L] : 0.f;
#pragma unroll
        for (int off = 32; off; off >>= 1) {
            ps += __shfl_xor(ps, off);
            pd += __shfl_xor(pd, off);
        }
        if (L == 0) { asrc[n] = ps; adst[n] = pd; }
    }
}

// ---------------------------------------------------------------------------
// Fused layer-2 aggregation + softmax denom + bias + log_softmax.
// ---------------------------------------------------------------------------
__global__ __launch_bounds__(256) void fagg2_k(
    const int* __restrict__ csr_src, const int* __restrict__ row_start,
    const float* __restrict__ asrc, const float* __restrict__ adst,
    const __half* __restrict__ h2h, const float* __restrict__ b2,
    float* __restrict__ out)
{
    int node = blockIdx.x * 4 + (threadIdx.x >> 6);
    int L = threadIdx.x & 63;
    bool act = L < 40;
    int col = act ? L : 0;
    int b = row_start[node], e = row_start[node + 1];
    float ad = adst[node];

    float a0 = 0.f, a1 = 0.f, a2 = 0.f, a3 = 0.f;
    float d0 = 0.f, d1 = 0.f, d2 = 0.f, d3 = 0.f;

    int j = b;
    for (; j + 3 < e; j += 4) {
        int s0 = csr_src[j], s1 = csr_src[j + 1], s2 = csr_src[j + 2], s3 = csr_src[j + 3];
        float w0 = wexp(asrc[s0] + ad);
        float w1 = wexp(asrc[s1] + ad);
        float w2 = wexp(asrc[s2] + ad);
        float w3 = wexp(asrc[s3] + ad);
        float x0 = __half2float(h2h[(size_t)s0 * 64 + col]);
        float x1 = __half2float(h2h[(size_t)s1 * 64 + col]);
        float x2 = __half2float(h2h[(size_t)s2 * 64 + col]);
        float x3 = __half2float(h2h[(size_t)s3 * 64 + col]);
        a0 += w0 * x0; d0 += w0;
        a1 += w1 * x1; d1 += w1;
        a2 += w2 * x2; d2 += w2;
        a3 += w3 * x3; d3 += w3;
    }
    for (; j < e; ++j) {
        int s = csr_src[j];
        float w = wexp(asrc[s] + ad);
        float xv = __half2float(h2h[(size_t)s * 64 + col]);
        a0 += w * xv; d0 += w;
    }

    float den = (d0 + d1) + (d2 + d3);
    float acc = (a0 + a1) + (a2 + a3);
    float v = act ? acc / (den + 1e-16f) + b2[L] : -1e30f;
    float mx = v;
#pragma unroll
    for (int off = 32; off; off >>= 1) mx = fmaxf(mx, __shfl_xor(mx, off));
    float ex = act ? __expf(v - mx) : 0.f;
#pragma unroll
    for (int off = 32; off; off >>= 1) ex += __shfl_xor(ex, off);
    if (act) out[(size_t)node * 40 + L] = v - mx - logf(ex);
}

// ---------------------------------------------------------------------------
extern "C" void kernel_launch(void* const* d_in, const int* in_sizes, int n_in,
                              void* d_out, int out_size, void* d_ws, size_t ws_size,
                              hipStream_t stream)
{
    const float* x   = (const float*)d_in[0];
    const int*   ei  = (const int*)d_in[1];
    const float* W1  = (const float*)d_in[2];
    const float* as1 = (const float*)d_in[3];
    const float* ad1 = (const float*)d_in[4];
    const float* b1  = (const float*)d_in[5];
    const float* W2  = (const float*)d_in[6];
    const float* as2 = (const float*)d_in[7];
    const float* ad2 = (const float*)d_in[8];
    const float* b2  = (const float*)d_in[9];
    float* out = (float*)d_out;

    float* ws = (float*)d_ws;
    // workspace layout (4B units); total ~23.8M = 95.2 MB
    __half* h1h  = (__half*)ws;                   // N*128 halves; reused as h2h (N*64 halves)
    float* out1  = ws + 6400000;                  // N*128
    float* asrc1 = ws + 19200000;                 // 2N
    float* adst1 = ws + 19400000;                 // 2N
    float* asrc2 = ws + 19600000;                 // N
    float* adst2 = ws + 19700000;                 // N
    int* bcur      = (int*)(ws + 19800000);       // NB
    int* bbase     = (int*)(ws + 19801000);       // NB
    int* row_start = (int*)(ws + 19802000);       // N+1
    int* csr_src   = (int*)(ws + 19910000);       // E_TOT
    unsigned* bdata = (unsigned*)(ws + 21700000); // NB*BCAP = 2.1M

    // zero bucket cursors only (2 KB)
    hipMemsetAsync(bcur, 0, NB * sizeof(int), stream);

    // CSR build: bin -> scan -> build (replaces count/scan x3/fill)
    bin_k<<<NBIN_WG, 256, 0, stream>>>(ei, bcur, bdata);
    scanb_k<<<1, 512, 0, stream>>>(bcur, bbase);
    build_k<<<NB, 256, 0, stream>>>(bdata, bcur, bbase, row_start, csr_src);

    // layer 1
    gemm1_k<<<3125, 256, 0, stream>>>(x, W1, as1, ad1, h1h, asrc1, adst1);
    fagg1_k<<<25000, 256, 0, stream>>>(csr_src, row_start, asrc1, adst1, h1h, b1, out1);

    // layer 2 (h2h reuses h1h region, stride 64 halves = one 128B line)
    __half* h2h = h1h;
    gemm2_k<<<3125, 256, 0, stream>>>(out1, W2, as2, ad2, h2h, asrc2, adst2);
    fagg2_k<<<25000, 256, 0, stream>>>(csr_src, row_start, asrc2, adst2, h2h, b2, out);
}